// Round 7
// baseline (2092.369 us; speedup 1.0000x reference)
//
#include <hip/hip_runtime.h>
#include <hip/hip_bf16.h>

// Elman RNN, round 7: ONE kernel, 256 blocks x 512 threads.
//   blocks 0..7   : the round-4 scan (measured best, 1207us) over batch-16 tiles,
//                   gated on 128-step chunks by a device-scope ready counter.
//   blocks 8..255 : produce xin[t][b][h] = bf16(log2e*(x W_in^T + b_in)) for
//                   (chunk, batch) units; __threadfence + atomicAdd signals.
// Rationale: the scan uses 8 CUs for ~1.2ms while 248 CUs idled; the serial
// xin pre-pass + launch gap cost ~256us every round. Producer work now hides
// entirely behind the scan's first chunks (chunk 0 ready in ~5us: 128 units
// in parallel on 128 CUs).
// Round-6 lesson kept: m-tile MFMA chains stay kt-major INTERLEAVED (in-order
// wave issue serializes dependent chains otherwise: +280cyc/step measured).

#define BATCH 128
#define SEQ   2048
#define NIN   128
#define NH    256
#define NOUT  128

#define BTILE 16
#define NSCAN 8                    // scan blocks (batch/16)
#define NPROD 248                  // producer blocks
#define CHUNK 128                  // timesteps per ready-gate
#define NCHUNK (SEQ / CHUNK)       // 16
#define NUNITS (NCHUNK * BATCH)    // 2048 producer units (chunk, b)
#define HPITCH 264                 // 256 + 8 pad (bf16)
#define XPITCH 136
#define LOG2E 1.4426950408889634f
#define XIN_ELEMS ((size_t)SEQ * BATCH * NH)

typedef __attribute__((ext_vector_type(8))) short short8;
typedef __attribute__((ext_vector_type(4))) float f32x4;

__device__ __forceinline__ uint pk_bf16(float a, float b) {
    float2 p; p.x = a; p.y = b;
    __hip_bfloat162 h = __float22bfloat162_rn(p);
    union { __hip_bfloat162 h; uint u; } v; v.h = h; return v.u;
}
__device__ __forceinline__ short8 load_wfrag_s(const float* __restrict__ W, int ld,
                                               int row, int col, float scale) {
    const float4* p = (const float4*)(W + (size_t)row * ld + col);
    float4 a = p[0], b = p[1];
    union { short8 v; uint u[4]; } r;
    r.u[0] = pk_bf16(a.x * scale, a.y * scale);
    r.u[1] = pk_bf16(a.z * scale, a.w * scale);
    r.u[2] = pk_bf16(b.x * scale, b.y * scale);
    r.u[3] = pk_bf16(b.z * scale, b.w * scale);
    return r.v;
}
__device__ __forceinline__ float bfhi2f(uint u) {
    union { uint u; float f; } v; v.u = u & 0xffff0000u; return v.f;
}
__device__ __forceinline__ float bflo2f(uint u) {
    union { uint u; float f; } v; v.u = u << 16; return v.f;
}

__global__ __launch_bounds__(512, 2)
void elman_fused_all(const float* __restrict__ x,
                     const float* __restrict__ W_in,
                     const float* __restrict__ b_in,
                     const float* __restrict__ W_rec,
                     const float* __restrict__ W_out,
                     const float* __restrict__ b_out,
                     ushort* __restrict__ xin,
                     int* __restrict__ cnt,          // [NCHUNK] ready counters
                     float* __restrict__ out) {
    const int tid  = threadIdx.x;
    const int lane = tid & 63;
    const int wid  = tid >> 6;          // 0..7
    const int n15  = lane & 15;
    const int q    = lane >> 4;

    __shared__ __align__(16) ushort hlds[2][BTILE * HPITCH];  // scan path only

    if (blockIdx.x >= NSCAN) {
        // ================= producer path: blocks 8..255 =================
        // wave wid owns hidden m-tiles {2wid, 2wid+1}; B n-axis = t (16-wide).
        short8 win[2][4];
        float  bias[2][4];
        #pragma unroll
        for (int mt = 0; mt < 2; ++mt) {
            const int row = (wid * 2 + mt) * 16 + n15;
            #pragma unroll
            for (int kt = 0; kt < 4; ++kt)
                win[mt][kt] = load_wfrag_s(W_in, NIN, row, kt * 32 + q * 8, LOG2E);
            #pragma unroll
            for (int r = 0; r < 4; ++r)
                bias[mt][r] = LOG2E * b_in[(wid * 2 + mt) * 16 + q * 4 + r];
        }

        for (int u = (int)blockIdx.x - NSCAN; u < NUNITS; u += NPROD) {
            const int chunk = u >> 7;          // 0..15 (ascending -> chunk 0 first)
            const int b     = u & 127;
            const int t0c   = chunk * CHUNK;

            #pragma unroll 1
            for (int it = 0; it < CHUNK / 16; ++it) {     // 8 x 16-t tiles
                const int tt = t0c + it * 16 + n15;        // this lane's t (n-axis)
                const float* xr = x + ((size_t)b * SEQ + tt) * NIN + q * 8;
                short8 bx[4];
                #pragma unroll
                for (int kt = 0; kt < 4; ++kt) {
                    const float4* p = (const float4*)(xr + kt * 32);
                    float4 a = p[0], c = p[1];
                    union { short8 v; uint u4[4]; } r;
                    r.u4[0] = pk_bf16(a.x, a.y); r.u4[1] = pk_bf16(a.z, a.w);
                    r.u4[2] = pk_bf16(c.x, c.y); r.u4[3] = pk_bf16(c.z, c.w);
                    bx[kt] = r.v;
                }
                f32x4 acc[2];
                #pragma unroll
                for (int mt = 0; mt < 2; ++mt) {
                    acc[mt][0] = bias[mt][0]; acc[mt][1] = bias[mt][1];
                    acc[mt][2] = bias[mt][2]; acc[mt][3] = bias[mt][3];
                }
                #pragma unroll
                for (int kt = 0; kt < 4; ++kt)
                    #pragma unroll
                    for (int mt = 0; mt < 2; ++mt)
                        acc[mt] = __builtin_amdgcn_mfma_f32_16x16x32_bf16(
                            win[mt][kt], bx[kt], acc[mt], 0, 0, 0);
                // C: col = t (n15), rows = hidden -> xin[t][b][h], 4 h per lane
                ushort* dst = xin + (size_t)tt * (BATCH * NH) + (size_t)b * NH + q * 4;
                #pragma unroll
                for (int mt = 0; mt < 2; ++mt) {
                    uint2 w;
                    w.x = pk_bf16(acc[mt][0], acc[mt][1]);
                    w.y = pk_bf16(acc[mt][2], acc[mt][3]);
                    *(uint2*)(dst + (wid * 2 + mt) * 16) = w;
                }
            }
            // release this unit's writes device-wide, then signal
            __threadfence();
            __syncthreads();
            if (tid == 0)
                __hip_atomic_fetch_add(&cnt[chunk], 1, __ATOMIC_RELEASE,
                                       __HIP_MEMORY_SCOPE_AGENT);
        }
        return;
    }

    // ================= scan path: blocks 0..7 (round-4 verbatim + gates) ========
    const int bblk = blockIdx.x * BTILE;

    short8 wrec[2][8];
    #pragma unroll
    for (int mt = 0; mt < 2; ++mt) {
        const int row = (wid * 2 + mt) * 16 + n15;
        #pragma unroll
        for (int kt = 0; kt < 8; ++kt)
            wrec[mt][kt] = load_wfrag_s(W_rec, NH, row, kt * 32 + q * 8, LOG2E);
    }

    for (int i = tid; i < BTILE * HPITCH / 2; i += 512)
        ((uint*)hlds[0])[i] = 0u;
    __syncthreads();

    const size_t xoff = (size_t)(bblk + n15) * NH + q * 4 + (wid * 2) * 16;  // +mt*16
    const size_t tstride = (size_t)BATCH * NH;

    #pragma unroll 1
    for (int k = 0; k < NCHUNK; ++k) {
        const int t0 = k * CHUNK;
        // gate: wait for all 128 batch-units of chunk k
        if (tid == 0) {
            while (__hip_atomic_load(&cnt[k], __ATOMIC_ACQUIRE,
                                     __HIP_MEMORY_SCOPE_AGENT) < BATCH)
                __builtin_amdgcn_s_sleep(2);
        }
        __syncthreads();

        // fresh xin for step t0 (chunk just became ready)
        uint2 xc[2], xn[2];
        {
            const ushort* p0 = xin + (size_t)t0 * tstride + xoff;
            xc[0] = *(const uint2*)(p0);
            xc[1] = *(const uint2*)(p0 + 16);
        }

        #pragma unroll 1
        for (int t = t0; t < t0 + CHUNK; ++t) {
            const int cur = t & 1, nxt = cur ^ 1;

            // distance-1 prefetch, clamped inside the ready chunk
            const int tp = (t + 1 < t0 + CHUNK) ? (t + 1) : (t0 + CHUNK - 1);
            const ushort* pp = xin + (size_t)tp * tstride + xoff;
            xn[0] = *(const uint2*)(pp);
            xn[1] = *(const uint2*)(pp + 16);

            short8 bh[8];
            #pragma unroll
            for (int kt = 0; kt < 8; ++kt)
                bh[kt] = *(const short8*)&hlds[cur][n15 * HPITCH + kt * 32 + q * 8];

            f32x4 acc[2];
            #pragma unroll
            for (int mt = 0; mt < 2; ++mt) {
                acc[mt][0] = bflo2f(xc[mt].x);
                acc[mt][1] = bfhi2f(xc[mt].x);
                acc[mt][2] = bflo2f(xc[mt].y);
                acc[mt][3] = bfhi2f(xc[mt].y);
            }
            // kt-major, mt-inner: two independent chains stay interleaved
            #pragma unroll
            for (int kt = 0; kt < 8; ++kt)
                #pragma unroll
                for (int mt = 0; mt < 2; ++mt)
                    acc[mt] = __builtin_amdgcn_mfma_f32_16x16x32_bf16(
                        wrec[mt][kt], bh[kt], acc[mt], 0, 0, 0);

            #pragma unroll
            for (int mt = 0; mt < 2; ++mt) {
                float h0 = __builtin_amdgcn_rcpf(1.0f + __builtin_amdgcn_exp2f(-acc[mt][0]));
                float h1 = __builtin_amdgcn_rcpf(1.0f + __builtin_amdgcn_exp2f(-acc[mt][1]));
                float h2 = __builtin_amdgcn_rcpf(1.0f + __builtin_amdgcn_exp2f(-acc[mt][2]));
                float h3 = __builtin_amdgcn_rcpf(1.0f + __builtin_amdgcn_exp2f(-acc[mt][3]));
                uint2 w; w.x = pk_bf16(h0, h1); w.y = pk_bf16(h2, h3);
                *(uint2*)&hlds[nxt][n15 * HPITCH + (wid * 2 + mt) * 16 + q * 4] = w;
            }

            xc[0] = xn[0]; xc[1] = xn[1];
            __syncthreads();
        }
    }

    // ---- output projection from hlds[0] (SEQ even): wave wid owns m-tile wid ----
    short8 wout[8];
    float  bo[4];
    {
        const int row = wid * 16 + n15;
        #pragma unroll
        for (int kt = 0; kt < 8; ++kt)
            wout[kt] = load_wfrag_s(W_out, NH, row, kt * 32 + q * 8, 1.0f);
        #pragma unroll
        for (int r = 0; r < 4; ++r)
            bo[r] = b_out[wid * 16 + q * 4 + r];
    }
    f32x4 oacc;
    oacc[0] = bo[0]; oacc[1] = bo[1]; oacc[2] = bo[2]; oacc[3] = bo[3];
    #pragma unroll
    for (int kt = 0; kt < 8; ++kt) {
        short8 bh = *(const short8*)&hlds[0][n15 * HPITCH + kt * 32 + q * 8];
        oacc = __builtin_amdgcn_mfma_f32_16x16x32_bf16(wout[kt], bh, oacc, 0, 0, 0);
    }
    #pragma unroll
    for (int r = 0; r < 4; ++r) {
        const int o = wid * 16 + q * 4 + r;
        out[(size_t)(bblk + n15) * NOUT + o] = oacc[r];
    }
}

// ---------------- Fallback (fully fused single-pass) if ws too small ------------
__global__ __launch_bounds__(256, 1)
void elman_mfma(const float* __restrict__ x,
                const float* __restrict__ W_in,
                const float* __restrict__ b_in,
                const float* __restrict__ W_rec,
                const float* __restrict__ W_out,
                const float* __restrict__ b_out,
                float* __restrict__ out) {
    const int tid  = threadIdx.x;
    const int lane = tid & 63;
    const int wid  = tid >> 6;
    const int n15  = lane & 15;
    const int q    = lane >> 4;
    const int bblk = blockIdx.x * BTILE;

    __shared__ __align__(16) ushort hlds[2][BTILE * HPITCH];
    __shared__ __align__(16) ushort xlds[2][BTILE * XPITCH];

    short8 wrec[4][8];
    short8 win[4][4];
    float  bias[4][4];
    #pragma unroll
    for (int mt = 0; mt < 4; ++mt) {
        const int row = (wid * 4 + mt) * 16 + n15;
        #pragma unroll
        for (int kt = 0; kt < 8; ++kt)
            wrec[mt][kt] = load_wfrag_s(W_rec, NH, row, kt * 32 + q * 8, 1.0f);
        #pragma unroll
        for (int kt = 0; kt < 4; ++kt)
            win[mt][kt] = load_wfrag_s(W_in, NIN, row, kt * 32 + q * 8, 1.0f);
        #pragma unroll
        for (int r = 0; r < 4; ++r)
            bias[mt][r] = b_in[(wid * 4 + mt) * 16 + q * 4 + r];
    }
    for (int i = tid; i < BTILE * HPITCH / 2; i += 256)
        ((uint*)hlds[0])[i] = 0u;

    const int xr = tid >> 4;
    const int xc = (tid & 15) * 8;
    const size_t xbase = ((size_t)(bblk + xr)) * SEQ * NIN + xc;
    {
        const float4* p = (const float4*)(x + xbase);
        float4 a = p[0], b = p[1];
        union { uint4 u4; uint s[4]; } px;
        px.s[0] = pk_bf16(a.x, a.y); px.s[1] = pk_bf16(a.z, a.w);
        px.s[2] = pk_bf16(b.x, b.y); px.s[3] = pk_bf16(b.z, b.w);
        *(uint4*)&xlds[0][xr * XPITCH + xc] = px.u4;
    }
    __syncthreads();

    #pragma unroll 1
    for (int t = 0; t < SEQ; ++t) {
        const int cur = t & 1, nxt = cur ^ 1;
        float4 xp0{}, xp1{};
        if (t + 1 < SEQ) {
            const float4* p = (const float4*)(x + xbase + (size_t)(t + 1) * NIN);
            xp0 = p[0]; xp1 = p[1];
        }
        short8 bx[4], bh[8];
        #pragma unroll
        for (int kt = 0; kt < 4; ++kt)
            bx[kt] = *(const short8*)&xlds[cur][n15 * XPITCH + kt * 32 + q * 8];
        #pragma unroll
        for (int kt = 0; kt < 8; ++kt)
            bh[kt] = *(const short8*)&hlds[cur][n15 * HPITCH + kt * 32 + q * 8];
        f32x4 acc[4];
        #pragma unroll
        for (int mt = 0; mt < 4; ++mt) {
            acc[mt][0] = bias[mt][0]; acc[mt][1] = bias[mt][1];
            acc[mt][2] = bias[mt][2]; acc[mt][3] = bias[mt][3];
        }
        #pragma unroll
        for (int kt = 0; kt < 4; ++kt)
            #pragma unroll
            for (int mt = 0; mt < 4; ++mt)
                acc[mt] = __builtin_amdgcn_mfma_f32_16x16x32_bf16(
                    win[mt][kt], bx[kt], acc[mt], 0, 0, 0);
        #pragma unroll
        for (int kt = 0; kt < 8; ++kt)
            #pragma unroll
            for (int mt = 0; mt < 4; ++mt)
                acc[mt] = __builtin_amdgcn_mfma_f32_16x16x32_bf16(
                    wrec[mt][kt], bh[kt], acc[mt], 0, 0, 0);
        #pragma unroll
        for (int mt = 0; mt < 4; ++mt) {
            float h0 = 1.0f / (1.0f + __expf(-acc[mt][0]));
            float h1 = 1.0f / (1.0f + __expf(-acc[mt][1]));
            float h2 = 1.0f / (1.0f + __expf(-acc[mt][2]));
            float h3 = 1.0f / (1.0f + __expf(-acc[mt][3]));
            uint2 w;
            w.x = pk_bf16(h0, h1);
            w.y = pk_bf16(h2, h3);
            *(uint2*)&hlds[nxt][n15 * HPITCH + (wid * 4 + mt) * 16 + q * 4] = w;
        }
        if (t + 1 < SEQ) {
            union { uint4 u4; uint s[4]; } px;
            px.s[0] = pk_bf16(xp0.x, xp0.y); px.s[1] = pk_bf16(xp0.z, xp0.w);
            px.s[2] = pk_bf16(xp1.x, xp1.y); px.s[3] = pk_bf16(xp1.z, xp1.w);
            *(uint4*)&xlds[nxt][xr * XPITCH + xc] = px.u4;
        }
        __syncthreads();
    }

    short8 wout[2][8];
    float  bo[2][4];
    #pragma unroll
    for (int mo = 0; mo < 2; ++mo) {
        const int row = (wid * 2 + mo) * 16 + n15;
        #pragma unroll
        for (int kt = 0; kt < 8; ++kt)
            wout[mo][kt] = load_wfrag_s(W_out, NH, row, kt * 32 + q * 8, 1.0f);
        #pragma unroll
        for (int r = 0; r < 4; ++r)
            bo[mo][r] = b_out[(wid * 2 + mo) * 16 + q * 4 + r];
    }
    f32x4 oacc[2];
    #pragma unroll
    for (int mo = 0; mo < 2; ++mo) {
        oacc[mo][0] = bo[mo][0]; oacc[mo][1] = bo[mo][1];
        oacc[mo][2] = bo[mo][2]; oacc[mo][3] = bo[mo][3];
    }
    #pragma unroll
    for (int kt = 0; kt < 8; ++kt) {
        short8 bh = *(const short8*)&hlds[0][n15 * HPITCH + kt * 32 + q * 8];
        #pragma unroll
        for (int mo = 0; mo < 2; ++mo)
            oacc[mo] = __builtin_amdgcn_mfma_f32_16x16x32_bf16(
                wout[mo][kt], bh, oacc[mo], 0, 0, 0);
    }
    #pragma unroll
    for (int mo = 0; mo < 2; ++mo)
        #pragma unroll
        for (int r = 0; r < 4; ++r) {
            const int o = (wid * 2 + mo) * 16 + q * 4 + r;
            out[(size_t)(bblk + n15) * NOUT + o] = oacc[mo][r];
        }
}

extern "C" void kernel_launch(void* const* d_in, const int* in_sizes, int n_in,
                              void* d_out, int out_size, void* d_ws, size_t ws_size,
                              hipStream_t stream) {
    const float* x     = (const float*)d_in[0];
    const float* W_in  = (const float*)d_in[1];
    const float* b_in  = (const float*)d_in[2];
    const float* W_rec = (const float*)d_in[3];
    const float* W_out = (const float*)d_in[4];
    const float* b_out = (const float*)d_in[5];
    float* out = (float*)d_out;

    const size_t xin_bytes = XIN_ELEMS * sizeof(ushort);          // 134 MB
    const size_t need = xin_bytes + NCHUNK * sizeof(int);
    if (ws_size >= need) {
        ushort* xin = (ushort*)d_ws;
        int* cnt = (int*)((char*)d_ws + xin_bytes);
        hipMemsetAsync(cnt, 0, NCHUNK * sizeof(int), stream);
        elman_fused_all<<<NSCAN + NPROD, 512, 0, stream>>>(
            x, W_in, b_in, W_rec, W_out, b_out, xin, cnt, out);
    } else {
        elman_mfma<<<NSCAN, 256, 0, stream>>>(x, W_in, b_in, W_rec, W_out, b_out, out);
    }
}